// Round 14
// baseline (507.893 us; speedup 1.0000x reference)
//
#include <hip/hip_runtime.h>
#include <hip/hip_bf16.h>
#include <math.h>

#define BATCH 8
#define LRAW 131072
#define L1P 32768
#define L2P 8192
#define SEQ 2048
#define DMODEL 256
#define NHEAD 8
#define DHEAD 32
#define MDIM 128
#define MHALF 64
#define DFF 1024
#define BS_TOK (BATCH*SEQ)
#define INV_SQRT_M 0.08838834764831845f

typedef __attribute__((ext_vector_type(8))) short s8v;   // 8 bf16 (4 VGPRs)
typedef __attribute__((ext_vector_type(4))) float f4v;   // MFMA accumulator

static __device__ __forceinline__ f4v mfma16(s8v a, s8v b, f4v c) {
    return __builtin_amdgcn_mfma_f32_16x16x32_bf16(a, b, c, 0, 0, 0);
}
static __device__ __forceinline__ unsigned short f2bf(float x) {
    __hip_bfloat16 h = __float2bfloat16(x);
    return *reinterpret_cast<unsigned short*>(&h);
}
static __device__ __forceinline__ float bf2f(unsigned short u) {
    __hip_bfloat16 h; *reinterpret_cast<unsigned short*>(&h) = u;
    return __bfloat162float(h);
}
static __device__ __forceinline__ void split8(const float* v, unsigned short* dh, unsigned short* dl) {
#pragma unroll
    for (int j = 0; j < 8; j++) {
        unsigned short hv = f2bf(v[j]);
        dh[j] = hv;
        dl[j] = f2bf(v[j] - bf2f(hv));
    }
}
static __device__ __forceinline__ void split_frag(const float* v, s8v& hi, s8v& lo) {
#pragma unroll
    for (int j = 0; j < 8; j++) {
        unsigned short hv = f2bf(v[j]);
        hi[j] = (short)hv;
        lo[j] = (short)f2bf(v[j] - bf2f(hv));
    }
}
// r5 LDS quad-swizzle (PASSED: conflicts 0 across all GEMMs since r6).
static __device__ __forceinline__ int swz(int row, int kq) {
    return row * 32 + ((kq ^ ((row >> 1) & 3)) << 3);
}
// r9: async global->LDS staging (16B/lane), per-lane pre-swizzled global
// source (m173 pattern). PASSED r10: total 554.8 -> 527.3.
static __device__ __forceinline__ void glds16(const unsigned short* g, unsigned short* l) {
    __builtin_amdgcn_global_load_lds(
        (const __attribute__((address_space(1))) void*)g,
        (__attribute__((address_space(3))) void*)l, 16, 0, 0);
}

// ================= conv stem (PASSED, verbatim) =================

__global__ __launch_bounds__(256) void conv0_kernel(const float* __restrict__ x,
    const float* __restrict__ w, const float* __restrict__ bias, float* __restrict__ out)
{
    int idx = blockIdx.x * 256 + threadIdx.x;
    if (idx >= BATCH * L1P) return;
    int b = idx >> 15;
    int p = idx & (L1P - 1);
    const float* xb = x + (size_t)b * LRAW;
    float acc[8];
#pragma unroll
    for (int c = 0; c < 8; c++) acc[c] = 0.f;
#pragma unroll
    for (int i = 0; i < 4; i++) {
        int base = 4 * p + i - 5;
        float y[8];
#pragma unroll
        for (int c = 0; c < 8; c++) y[c] = bias[c];
#pragma unroll
        for (int kk = 0; kk < 11; kk++) {
            int xi = base + kk;
            float xv = (xi >= 0 && xi < LRAW) ? xb[xi] : 0.f;
#pragma unroll
            for (int c = 0; c < 8; c++) y[c] = fmaf(xv, w[kk * 8 + c], y[c]);
        }
#pragma unroll
        for (int c = 0; c < 8; c++) acc[c] += fmaxf(y[c], 0.f);
    }
    float* op = out + (size_t)idx * 8;
#pragma unroll
    for (int c = 0; c < 8; c++) op[c] = acc[c] * 0.25f;
}

__global__ __launch_bounds__(256) void conv1_kernel(const float* __restrict__ in,
    const float* __restrict__ w, const float* __restrict__ bias, float* __restrict__ out)
{
    int idx = blockIdx.x * 256 + threadIdx.x;
    if (idx >= BATCH * L2P) return;
    int b = idx >> 13;
    int p = idx & (L2P - 1);
    const float* ib = in + (size_t)b * L1P * 8;
    float acc[16];
#pragma unroll
    for (int c = 0; c < 16; c++) acc[c] = 0.f;
#pragma unroll
    for (int i = 0; i < 4; i++) {
        float y[16];
#pragma unroll
        for (int c = 0; c < 16; c++) y[c] = bias[c];
#pragma unroll
        for (int kk = 0; kk < 3; kk++) {
            int pos = 4 * p + i + kk - 1;
            if (pos < 0 || pos >= L1P) continue;
            const float* row = ib + (size_t)pos * 8;
#pragma unroll
            for (int ci = 0; ci < 8; ci++) {
                float xv = row[ci];
#pragma unroll
                for (int c = 0; c < 16; c++) y[c] = fmaf(xv, w[(kk * 8 + ci) * 16 + c], y[c]);
            }
        }
#pragma unroll
        for (int c = 0; c < 16; c++) acc[c] += fmaxf(y[c], 0.f);
    }
    float* op = out + (size_t)idx * 16;
#pragma unroll
    for (int c = 0; c < 16; c++) op[c] = acc[c] * 0.25f;
}

__global__ __launch_bounds__(256) void conv2_kernel(const float* __restrict__ in,
    const float* __restrict__ w, const float* __restrict__ bias, float* __restrict__ out)
{
    int bp = blockIdx.x;
    int b = bp / SEQ, p = bp % SEQ;
    int co = threadIdx.x;
    __shared__ float win[6][16];
    int t = threadIdx.x;
    if (t < 96) {
        int r = t / 16, ci = t % 16;
        int pos = 4 * p - 1 + r;
        win[r][ci] = (pos >= 0 && pos < L2P) ? in[((size_t)b * L2P + pos) * 16 + ci] : 0.f;
    }
    __syncthreads();
    float y[4];
#pragma unroll
    for (int i = 0; i < 4; i++) y[i] = bias[co];
#pragma unroll
    for (int kk = 0; kk < 3; kk++) {
#pragma unroll
        for (int ci = 0; ci < 16; ci++) {
            float wv = w[(kk * 16 + ci) * 256 + co];
#pragma unroll
            for (int i = 0; i < 4; i++) y[i] = fmaf(win[i + kk][ci], wv, y[i]);
        }
    }
    float acc = 0.f;
#pragma unroll
    for (int i = 0; i < 4; i++) acc += fmaxf(y[i], 0.f);
    out[((size_t)b * SEQ + p) * 256 + co] = acc * 0.25f;
}

// ================= batched weight transpose+split =================
// r13: hoisted out of the layer loop -- weights are activation-independent,
// so both layers preprocess upfront (z encodes layer). 4 dispatches -> 2.

__global__ __launch_bounds__(256) void tconv4_kernel(
    const float* __restrict__ Wk, const float* __restrict__ Wv,
    const float* __restrict__ Wq, const float* __restrict__ Wo,
    unsigned short* __restrict__ dst)
{
    int z = blockIdx.z;
    int lay = z >> 2, sel = z & 3;
    const float* in = ((sel == 0) ? Wk : (sel == 1) ? Wv : (sel == 2) ? Wq : Wo)
                      + (size_t)lay * DMODEL * DMODEL;
    unsigned short* outs = dst + (size_t)lay * 524288 + (size_t)sel * 131072;
    const int R = 256, C = 256;
    __shared__ float tile[32][33];
    int t = threadIdx.x;
    int r0 = blockIdx.y * 32, c0 = blockIdx.x * 32;
    int r = t >> 3, cq = t & 7;
    float4 v = *(const float4*)(in + (size_t)(r0 + r) * C + c0 + cq * 4);
    tile[r][cq * 4 + 0] = v.x; tile[r][cq * 4 + 1] = v.y;
    tile[r][cq * 4 + 2] = v.z; tile[r][cq * 4 + 3] = v.w;
    __syncthreads();
    ushort4 hi, lo;
    unsigned short* hp = (unsigned short*)&hi;
    unsigned short* lp = (unsigned short*)&lo;
#pragma unroll
    for (int j = 0; j < 4; j++) {
        float x = tile[cq * 4 + j][r];
        hp[j] = f2bf(x);
        lp[j] = f2bf(x - bf2f(hp[j]));
    }
    size_t ob = (size_t)(c0 + r) * (2 * R) + r0 + cq * 4;
    *(ushort4*)&outs[ob] = hi;
    *(ushort4*)&outs[ob + R] = lo;
}

__global__ __launch_bounds__(256) void tconv_ff_kernel(
    const float* __restrict__ W1, const float* __restrict__ W2,
    unsigned short* __restrict__ w1t, unsigned short* __restrict__ w2t)
{
    int zf = blockIdx.z;
    int lay = zf >> 1, z = zf & 1;
    int bx = z ? blockIdx.y : blockIdx.x;
    int by = z ? blockIdx.x : blockIdx.y;
    const float* in = (z ? W2 : W1) + (size_t)lay * DMODEL * DFF;
    unsigned short* outs = (z ? w2t : w1t) + (size_t)lay * 524288;
    int R = z ? 1024 : 256;
    int C = z ? 256 : 1024;
    __shared__ float tile[32][33];
    int t = threadIdx.x;
    int r0 = by * 32, c0 = bx * 32;
    int r = t >> 3, cq = t & 7;
    float4 v = *(const float4*)(in + (size_t)(r0 + r) * C + c0 + cq * 4);
    tile[r][cq * 4 + 0] = v.x; tile[r][cq * 4 + 1] = v.y;
    tile[r][cq * 4 + 2] = v.z; tile[r][cq * 4 + 3] = v.w;
    __syncthreads();
    ushort4 hi, lo;
    unsigned short* hp = (unsigned short*)&hi;
    unsigned short* lp = (unsigned short*)&lo;
#pragma unroll
    for (int j = 0; j < 4; j++) {
        float x = tile[cq * 4 + j][r];
        hp[j] = f2bf(x);
        lp[j] = f2bf(x - bf2f(hp[j]));
    }
    size_t ob = (size_t)(c0 + r) * (2 * R) + r0 + cq * 4;
    *(ushort4*)&outs[ob] = hi;
    *(ushort4*)&outs[ob + R] = lo;
}

// ================= r4: hoisted LayerCentering + bf16-split =================

__global__ __launch_bounds__(256) void center_split(
    const float* __restrict__ hc, unsigned short* __restrict__ hcs)
{
    __shared__ float psum[64][4];
    __shared__ float muS[64];
    const int t = threadIdx.x;
    const int row = t >> 2, q4 = t & 3;
    const size_t grow = (size_t)blockIdx.x * 64 + row;
    const float* rp = hc + grow * DMODEL + q4 * 64;
    float4 va[16];
    float s = 0.f;
#pragma unroll
    for (int j = 0; j < 16; j++) {
        va[j] = *(const float4*)(rp + j * 4);
        s += va[j].x + va[j].y + va[j].z + va[j].w;
    }
    psum[row][q4] = s;
    __syncthreads();
    if (t < 64) muS[t] = (psum[t][0] + psum[t][1] + psum[t][2] + psum[t][3]) * (1.0f / 256.0f);
    __syncthreads();
    const float mu = muS[row];
    unsigned short* op = hcs + grow * 512 + q4 * 64;
#pragma unroll
    for (int j = 0; j < 8; j++) {
        float v[8] = {va[2*j].x - mu, va[2*j].y - mu, va[2*j].z - mu, va[2*j].w - mu,
                      va[2*j+1].x - mu, va[2*j+1].y - mu, va[2*j+1].z - mu, va[2*j+1].w - mu};
        unsigned short hb[8], lb[8];
        split8(v, hb, lb);
        *(uint4*)(op + j * 8) = *(const uint4*)hb;
        *(uint4*)(op + 256 + j * 8) = *(const uint4*)lb;
    }
}

// ================= split-bf16 MFMA GEMMs (r10/r11/r12 BK=64 structures) =================

template<bool RESID>
__global__ __launch_bounds__(256) void gemm12864(
    const unsigned short* __restrict__ Abuf, int ARS, int ALO,
    const unsigned short* __restrict__ Bbuf, int BRS, int BLO,
    const float* __restrict__ bias, const float* __restrict__ resid,
    float* __restrict__ C, int N, int K)
{
    __shared__ unsigned short AsH[2][128 * 32];
    __shared__ unsigned short AsL[2][128 * 32];
    __shared__ unsigned short BsH[2][64 * 32];
    __shared__ unsigned short BsL[2][64 * 32];
    const int t = threadIdx.x;
    const int n0 = blockIdx.y * 64, m0 = blockIdx.x * 128;   // m fast-varying
    const int lane = t & 63, w = t >> 6;
    const int wm = w & 1, wn = w >> 1, m16 = lane & 15, q = lane >> 4;
    const f4v fz = {0.f, 0.f, 0.f, 0.f};
    f4v acc[4][2];
#pragma unroll
    for (int i = 0; i < 4; i++)
#pragma unroll
        for (int j = 0; j < 2; j++) acc[i][j] = fz;
    const int rsw = lane >> 2;
    const int kqsw = (((lane & 3) ^ ((lane >> 3) & 3)) << 3);
    const unsigned short* gsrc =
        (w == 0) ? Abuf + (size_t)(m0 + rsw) * ARS + kqsw :
        (w == 1) ? Abuf + (size_t)(m0 + rsw) * ARS + ALO + kqsw :
        (w == 2) ? Bbuf + (size_t)(n0 + rsw) * BRS + kqsw :
                   Bbuf + (size_t)(n0 + rsw) * BRS + BLO + kqsw;
    const int gRS = (w < 2) ? ARS : BRS;
    unsigned short* ldst0 = (w == 0) ? AsH[0] : (w == 1) ? AsL[0] : (w == 2) ? BsH[0] : BsL[0];
    unsigned short* ldst1 = (w == 0) ? AsH[1] : (w == 1) ? AsL[1] : (w == 2) ? BsH[1] : BsL[1];
    for (int k0 = 0; k0 < K; k0 += 64) {
        __syncthreads();
        if (w < 2) {
#pragma unroll
            for (int i = 0; i < 8; i++) {
                glds16(gsrc + (size_t)(i * 16) * gRS + k0, ldst0 + i * 512);
                glds16(gsrc + (size_t)(i * 16) * gRS + k0 + 32, ldst1 + i * 512);
            }
        } else {
#pragma unroll
            for (int i = 0; i < 4; i++) {
                glds16(gsrc + (size_t)(i * 16) * gRS + k0, ldst0 + i * 512);
                glds16(gsrc + (size_t)(i * 16) * gRS + k0 + 32, ldst1 + i * 512);
            }
        }
        __syncthreads();
#pragma unroll
        for (int half = 0; half < 2; half++) {
            s8v ah[4], al[4], bh[2], bl[2];
#pragma unroll
            for (int i = 0; i < 4; i++) {
                int ar = wm * 64 + i * 16 + m16;
                int ro = swz(ar, q);
                ah[i] = *(const s8v*)&AsH[half][ro];
                al[i] = *(const s8v*)&AsL[half][ro];
            }
#pragma unroll
            for (int j = 0; j < 2; j++) {
                int br = wn * 32 + j * 16 + m16;
                int co = swz(br, q);
                bh[j] = *(const s8v*)&BsH[half][co];
                bl[j] = *(const s8v*)&BsL[half][co];
            }
#pragma unroll
            for (int mt = 0; mt < 4; mt++)
#pragma unroll
                for (int nt = 0; nt < 2; nt++) {
                    acc[mt][nt] = mfma16(ah[mt], bh[nt], acc[mt][nt]);
                    acc[mt][nt] = mfma16(ah[mt], bl[nt], acc[mt][nt]);
                    acc[mt][nt] = mfma16(al[mt], bh[nt], acc[mt][nt]);
                }
        }
    }
#pragma unroll
    for (int mt = 0; mt < 4; mt++)
#pragma unroll
        for (int nt = 0; nt < 2; nt++)
#pragma unroll
            for (int r = 0; r < 4; r++) {
                int rg = m0 + wm * 64 + mt * 16 + q * 4 + r;
                int cg = n0 + wn * 32 + nt * 16 + m16;
                float val = acc[mt][nt][r] + bias[cg];
                if (RESID) val += resid[(size_t)rg * N + cg];
                C[(size_t)rg * N + cg] = val;
            }
}

// r11: FF1 on the gemm12864 BK=64 structure; relu + split-bf16 out to usp.
__global__ __launch_bounds__(256) void gemm12864_ff1(
    const unsigned short* __restrict__ Abuf, const unsigned short* __restrict__ Bbuf,
    const float* __restrict__ bias, unsigned short* __restrict__ Us)
{
    __shared__ unsigned short AsH[2][128 * 32];
    __shared__ unsigned short AsL[2][128 * 32];
    __shared__ unsigned short BsH[2][64 * 32];
    __shared__ unsigned short BsL[2][64 * 32];
    const int t = threadIdx.x;
    const int n0 = blockIdx.y * 64, m0 = blockIdx.x * 128;   // m fast-varying
    const int lane = t & 63, w = t >> 6;
    const int wm = w & 1, wn = w >> 1, m16 = lane & 15, q = lane >> 4;
    const f4v fz = {0.f, 0.f, 0.f, 0.f};
    f4v acc[4][2];
#pragma unroll
    for (int i = 0; i < 4; i++)
#pragma unroll
        for (int j = 0; j < 2; j++) acc[i][j] = fz;
    const int rsw = lane >> 2;
    const int kqsw = (((lane & 3) ^ ((lane >> 3) & 3)) << 3);
    const unsigned short* gsrc =
        (w == 0) ? Abuf + (size_t)(m0 + rsw) * 512 + kqsw :
        (w == 1) ? Abuf + (size_t)(m0 + rsw) * 512 + 256 + kqsw :
        (w == 2) ? Bbuf + (size_t)(n0 + rsw) * 512 + kqsw :
                   Bbuf + (size_t)(n0 + rsw) * 512 + 256 + kqsw;
    unsigned short* ldst0 = (w == 0) ? AsH[0] : (w == 1) ? AsL[0] : (w == 2) ? BsH[0] : BsL[0];
    unsigned short* ldst1 = (w == 0) ? AsH[1] : (w == 1) ? AsL[1] : (w == 2) ? BsH[1] : BsL[1];
    for (int k0 = 0; k0 < 256; k0 += 64) {
        __syncthreads();
        if (w < 2) {
#pragma unroll
            for (int i = 0; i < 8; i++) {
                glds16(gsrc + (size_t)(i * 16) * 512 + k0, ldst0 + i * 512);
                glds16(gsrc + (size_t)(i * 16) * 512 + k0 + 32, ldst1 + i * 512);
            }
        } else {
#pragma unroll
            for (int i = 0; i < 4; i++) {
                glds16(gsrc + (size_t)(i * 16) * 512 + k0, ldst0 + i * 512);
                glds16(gsrc + (size_t)(i * 16) * 512 + k0 + 32, ldst1 + i * 512);
            }
        }
        __syncthreads();
#pragma unroll
        for (int half = 0; half < 2; half++) {
            s8v ah[4], al[4], bh[2], bl[2];
#pragma unroll
            for (int i = 0; i < 4; i++) {
                int ar = wm * 64 + i * 16 + m16;
                int ro = swz(ar, q);
                ah[i] = *(const s8v*)&AsH[half][ro];
                al[i] = *(const s8v*)&AsL[half][ro];
            }
#pragma unroll
            for (int j = 0; j < 2; j++) {
                int br = wn * 32 + j * 16 + m16;
                int co = swz(br, q);
                bh[j] = *(const s8v*)&BsH[half][co];
                bl[j] = *(const s8v*)&BsL[half][co];
            }
#pragma unroll
            for (int mt = 0; mt < 4; mt++)
#pragma unroll
                for (int nt = 0; nt < 2; nt++) {
                    acc[mt][nt] = mfma16(ah[mt], bh[nt], acc[mt][nt]);
                    acc[mt][nt] = mfma16(ah[mt], bl[nt], acc[mt][nt]);
                    acc[mt][nt] = mfma16(al[mt], bh[nt], acc[mt][nt]);
                }
        }
    }
#pragma unroll
    for (int mt = 0; mt < 4; mt++)
#pragma unroll
        for (int nt = 0; nt < 2; nt++)
#pragma unroll
            for (int r = 0; r < 4; r++) {
                int rg = m0 + wm * 64 + mt * 16 + q * 4 + r;
                int cg = n0 + wn * 32 + nt * 16 + m16;
                float val = fmaxf(acc[mt][nt][r] + bias[cg], 0.f);
                unsigned short hv = f2bf(val);
                Us[(size_t)rg * 2048 + cg] = hv;
                Us[(size_t)rg * 2048 + 1024 + cg] = f2bf(val - bf2f(hv));
            }
}

// r12: QKV on the gemm12864 BK=64 structure; bias-select epilogue, C f32.
__global__ __launch_bounds__(256) void gemm12864_qkv(
    const unsigned short* __restrict__ Abuf, const unsigned short* __restrict__ Bbuf,
    const float* __restrict__ bk, const float* __restrict__ bv, const float* __restrict__ bq,
    float* __restrict__ C)
{
    __shared__ unsigned short AsH[2][128 * 32];
    __shared__ unsigned short AsL[2][128 * 32];
    __shared__ unsigned short BsH[2][64 * 32];
    __shared__ unsigned short BsL[2][64 * 32];
    const int t = threadIdx.x;
    const int n0 = blockIdx.y * 64, m0 = blockIdx.x * 128;   // m fast-varying
    const int lane = t & 63, w = t >> 6;
    const int wm = w & 1, wn = w >> 1, m16 = lane & 15, q = lane >> 4;
    const f4v fz = {0.f, 0.f, 0.f, 0.f};
    f4v acc[4][2];
#pragma unroll
    for (int i = 0; i < 4; i++)
#pragma unroll
        for (int j = 0; j < 2; j++) acc[i][j] = fz;
    const int rsw = lane >> 2;
    const int kqsw = (((lane & 3) ^ ((lane >> 3) & 3)) << 3);
    const unsigned short* gsrc =
        (w == 0) ? Abuf + (size_t)(m0 + rsw) * 512 + kqsw :
        (w == 1) ? Abuf + (size_t)(m0 + rsw) * 512 + 256 + kqsw :
        (w == 2) ? Bbuf + (size_t)(n0 + rsw) * 512 + kqsw :
                   Bbuf + (size_t)(n0 + rsw) * 512 + 256 + kqsw;
    unsigned short* ldst0 = (w == 0) ? AsH[0] : (w == 1) ? AsL[0] : (w == 2) ? BsH[0] : BsL[0];
    unsigned short* ldst1 = (w == 0) ? AsH[1] : (w == 1) ? AsL[1] : (w == 2) ? BsH[1] : BsL[1];
    for (int k0 = 0; k0 < 256; k0 += 64) {
        __syncthreads();
        if (w < 2) {
#pragma unroll
            for (int i = 0; i < 8; i++) {
                glds16(gsrc + (size_t)(i * 16) * 512 + k0, ldst0 + i * 512);
                glds16(gsrc + (size_t)(i * 16) * 512 + k0 + 32, ldst1 + i * 512);
            }
        } else {
#pragma unroll
            for (int i = 0; i < 4; i++) {
                glds16(gsrc + (size_t)(i * 16) * 512 + k0, ldst0 + i * 512);
                glds16(gsrc + (size_t)(i * 16) * 512 + k0 + 32, ldst1 + i * 512);
            }
        }
        __syncthreads();
#pragma unroll
        for (int half = 0; half < 2; half++) {
            s8v ah[4], al[4], bh[2], bl[2];
#pragma unroll
            for (int i = 0; i < 4; i++) {
                int ar = wm * 64 + i * 16 + m16;
                int ro = swz(ar, q);
                ah[i] = *(const s8v*)&AsH[half][ro];
                al[i] = *(const s8v*)&AsL[half][ro];
            }
#pragma unroll
            for (int j = 0; j < 2; j++) {
                int br = wn * 32 + j * 16 + m16;
                int co = swz(br, q);
                bh[j] = *(const s8v*)&BsH[half][co];
                bl[j] = *(const s8v*)&BsL[half][co];
            }
#pragma unroll
            for (int mt = 0; mt < 4; mt++)
#pragma unroll
                for (int nt = 0; nt < 2; nt++) {
                    acc[mt][nt] = mfma16(ah[mt], bh[nt], acc[mt][nt]);
                    acc[mt][nt] = mfma16(ah[mt], bl[nt], acc[mt][nt]);
                    acc[mt][nt] = mfma16(al[mt], bh[nt], acc[mt][nt]);
                }
        }
    }
    const float* bp = (n0 < 256) ? bk : (n0 < 512) ? (bv - 256) : (bq - 512);
#pragma unroll
    for (int mt = 0; mt < 4; mt++)
#pragma unroll
        for (int nt = 0; nt < 2; nt++)
#pragma unroll
            for (int r = 0; r < 4; r++) {
                int rg = m0 + wm * 64 + mt * 16 + q * 4 + r;
                int cg = n0 + wn * 32 + nt * 16 + m16;
                C[(size_t)rg * 768 + cg] = acc[mt][nt][r] + bp[cg];
            }
}

// ================= phi kernels =================

// r6: full-MFMA phi_kv (PASSED r7: left the top-5, total -39us).
__global__ __launch_bounds__(256) void phi_kv_chunk(
    const float* __restrict__ qkv, const float* __restrict__ om_l,
    const float* __restrict__ g_l, float* __restrict__ part)
{
    __shared__ unsigned short ktTH[128 * 40];  // [feature m][tok], pitch 40
    __shared__ unsigned short ktTL[128 * 40];
    __shared__ unsigned short vTH[32 * 40];    // [e][tok], pitch 40
    __shared__ unsigned short vTL[32 * 40];

    const int bx = blockIdx.x;
    const int sub = bx & 15;
    const int bh = bx >> 4;               // 0..63
    const int b = bh >> 3, h = bh & 7;
    const int t = threadIdx.x;
    const float g = g_l[h];
    const int row0 = b * 2048 + sub * 128;

    const int w = t >> 6, lane = t & 63, m16 = lane & 15, q = lane >> 4;
    const int mh = w * 16 + m16;          // wave's proj feature column (0..63)
    const int ve = t & 31, vtq = t >> 5;  // vT staging: e, tok-base

    s8v obh, obl;
    {
        const float* op = om_l + (size_t)h * 2048 + (q * 8) * 64 + mh;
        float vv[8];
#pragma unroll
        for (int jj = 0; jj < 8; jj++) vv[jj] = op[jj * 64];
        split_frag(vv, obh, obl);
    }
    const float slope = 2.0f - (float)mh * 0.03125f;

    const f4v fz = {0.f, 0.f, 0.f, 0.f};
    f4v acc[2][2] = {{fz, fz}, {fz, fz}};

    for (int step = 0; step < 4; step++) {
        if (step) __syncthreads();

#pragma unroll
        for (int j = 0; j < 4; j++) {
            int tok = vtq + 8 * j;
            float v = qkv[(size_t)(row0 + step * 32 + tok) * 768 + 256 + h * 32 + ve];
            unsigned short hv = f2bf(v);
            vTH[ve * 40 + tok] = hv;
            vTL[ve * 40 + tok] = f2bf(v - bf2f(hv));
        }

        f4v pr[2] = {fz, fz};
#pragma unroll
        for (int tau = 0; tau < 2; tau++) {
            const float* kp = qkv + (size_t)(row0 + step * 32 + tau * 16 + m16) * 768 + h * 32 + q * 8;
            float4 v0 = *(const float4*)kp;
            float4 v1 = *(const float4*)(kp + 4);
            float vv[8] = {v0.x, v0.y, v0.z, v0.w, v1.x, v1.y, v1.z, v1.w};
            s8v kah, kal;
            split_frag(vv, kah, kal);
            pr[tau] = mfma16(kah, obh, pr[tau]);
            pr[tau] = mfma16(kah, obl, pr[tau]);
            pr[tau] = mfma16(kal, obh, pr[tau]);
        }

#pragma unroll
        for (int tau = 0; tau < 2; tau++)
#pragma unroll
            for (int r = 0; r < 4; r++) {
                int tokl = tau * 16 + q * 4 + r;
                float t_s = (float)(sub * 128 + step * 32 + tokl) * (1.0f / 2047.0f);
                float proj = pr[tau][r];
                float ec = INV_SQRT_M * __expf(-g * t_s * slope);
                float es = INV_SQRT_M * __expf(-g * (1.0f - t_s) * slope);
                float bc = __cosf(proj) * ec;
                float bs = __sinf(proj) * es;
                unsigned short bch = f2bf(bc), bsh = f2bf(bs);
                unsigned short bcl = f2bf(bc - bf2f(bch)), bsl = f2bf(bs - bf2f(bsh));
                ktTH[mh * 40 + tokl] = bch;
                ktTL[mh * 40 + tokl] = bcl;
                ktTH[(64 + mh) * 40 + tokl] = bsh;
                ktTL[(64 + mh) * 40 + tokl] = bsl;
            }
        __syncthreads();

        s8v aH[2], aL[2], bH[2], bL[2];
#pragma unroll
        for (int tau = 0; tau < 2; tau++) {
            int ro = (w * 32 + tau * 16 + m16) * 40 + q * 8;
            aH[tau] = *(const s8v*)&ktTH[ro];
            aL[tau] = *(const s8v*)&ktTL[ro];
        }
#pragma unroll
        for (int nu = 0; nu < 2; nu++) {
            int co = (nu * 16 + m16) * 40 + q * 8;
            bH[nu] = *(const s8v*)&vTH[co];
            bL[nu] = *(const s8v*)&vTL[co];
        }
#pragma unroll
        for (int tau = 0; tau < 2; tau++)
#pragma unroll
            for (int nu = 0; nu < 2; nu++) {
                acc[tau][nu] = mfma16(aH[tau], bH[nu], acc[tau][nu]);
                acc[tau][nu] = mfma16(aH[tau], bL[nu], acc[tau][nu]);
                acc[tau][nu] = mfma16(aL[tau], bH[nu], acc[tau][nu]);
            }
    }

    float* pp = part + (size_t)(bh * 16 + sub) * 4096;
#pragma unroll
    for (int tau = 0; tau < 2; tau++)
#pragma unroll
        for (int nu = 0; nu < 2; nu++)
#pragma unroll
            for (int r = 0; r < 4; r++) {
                int m = w * 32 + tau * 16 + q * 4 + r;
                int e = nu * 16 + m16;
                pp[m * 32 + e] = acc[tau][nu][r];
            }
}

// 1024 blocks (64 bh x 16 seg); independent-batch loads, fixed-order sum
__global__ __launch_bounds__(256) void kv_reduce(const float* __restrict__ part,
    float* __restrict__ kvf)
{
    int bh = blockIdx.x >> 4;
    int seg = blockIdx.x & 15;
    int i = seg * 256 + threadIdx.x;
    const float* base = part + (size_t)(bh * 16) * 4096 + i;
    float v[16];
#pragma unroll
    for (int sub = 0; sub < 16; sub++)
        v[sub] = base[(size_t)sub * 4096];
    float s = 0.f;
#pragma unroll
    for (int sub = 0; sub < 16; sub++) s += v[sub];
    kvf[(size_t)bh * 4096 + i] = s;
}

// r3: full-MFMA phi_o (PASSED r4: left the top-5).
__global__ __launch_bounds__(256, 3) void phi_o_chunk(
    const float* __restrict__ qkv, const float* __restrict__ kvf,
    const float* __restrict__ om_l, const float* __restrict__ g_l,
    unsigned short* __restrict__ osplit)
{
    __shared__ unsigned short qtH[128][72];
    __shared__ unsigned short qtL[128][72];
    __shared__ unsigned short kvbH[32][72];
    __shared__ unsigned short kvbL[32][72];

    const int bx = blockIdx.x;
    const int sub = bx & 15;
    const int bh = bx >> 4;
    const int b = bh >> 3, h = bh & 7;
    const int t = threadIdx.x;
    const float g = g_l[h];
    const int row0 = b * 2048 + sub * 128;

    const int w = t >> 6, lane = t & 63, m16 = lane & 15, q = lane >> 4;
    const int tokb = w * 32;

    s8v qah[2], qal[2];
#pragma unroll
    for (int tau = 0; tau < 2; tau++) {
        const float* qp = qkv + (size_t)(row0 + tokb + tau * 16 + m16) * 768 + 512 + h * 32 + q * 8;
        float4 v0 = *(const float4*)qp;
        float4 v1 = *(const float4*)(qp + 4);
        float vv[8] = {v0.x, v0.y, v0.z, v0.w, v1.x, v1.y, v1.z, v1.w};
        split_frag(vv, qah[tau], qal[tau]);
    }

    const f4v fz = {0.f, 0.f, 0.f, 0.f};
    f4v acc[2][2] = {{fz, fz}, {fz, fz}};

    for (int p = 0; p < 2; p++) {
        if (p) __syncthreads();

#pragma unroll
        for (int vi = 0; vi < 4; vi++) {
            int pidx = t + vi * 256;
            int e = pidx & 31, j = pidx >> 5;
            float c = kvf[(size_t)bh * 4096 + (p * 32 + j) * 32 + e];
            float s = kvf[(size_t)bh * 4096 + (64 + p * 32 + j) * 32 + e];
            unsigned short ch = f2bf(c), sh = f2bf(s);
            unsigned short cl = f2bf(c - bf2f(ch)), sl = f2bf(s - bf2f(sh));
            *(unsigned*)&kvbH[e][2 * j] = (unsigned)ch | ((unsigned)sh << 16);
            *(unsigned*)&kvbL[e][2 * j] = (unsigned)cl | ((unsigned)sl << 16);
        }

        s8v obh[2], obl[2];
#pragma unroll
        for (int mu = 0; mu < 2; mu++) {
            int mh_g = p * 32 + mu * 16 + m16;
            const float* op = om_l + (size_t)h * 2048 + (q * 8) * 64 + mh_g;
            float vv[8];
#pragma unroll
            for (int jj = 0; jj < 8; jj++) vv[jj] = op[jj * 64];
            split_frag(vv, obh[mu], obl[mu]);
        }

        f4v pr[2][2] = {{fz, fz}, {fz, fz}};
#pragma unroll
        for (int tau = 0; tau < 2; tau++)
#pragma unroll
            for (int mu = 0; mu < 2; mu++) {
                pr[tau][mu] = mfma16(qah[tau], obh[mu], pr[tau][mu]);
                pr[tau][mu] = mfma16(qah[tau], obl[mu], pr[tau][mu]);
                pr[tau][mu] = mfma16(qal[tau], obh[mu], pr[tau][mu]);
            }

#pragma unroll
        for (int tau = 0; tau < 2; tau++)
#pragma unroll
            for (int mu = 0; mu < 2; mu++) {
                int mf = mu * 16 + m16;
                int mh_g = p * 32 + mf;
                float slope = 2.0f - (float)mh_g * 0.03125f;
#pragma unroll
                for (int r = 0; r < 4; r++) {
                    int tokr = tokb + tau * 16 + q * 4 + r;
                    float t_s = (float)(sub * 128 + tokr) * (1.0f / 2047.0f);
                    float proj = pr[tau][mu][r];
                    float ec = INV_SQRT_M * __expf(g * t_s * slope);
                    float es = INV_SQRT_M * __expf(g * (1.0f - t_s) * slope);
                    float bc = __cosf(proj) * ec;
                    float bs = __sinf(proj) * es;
                    unsigned short bch = f2bf(bc), bsh = f2bf(bs);
                    unsigned short bcl = f2bf(bc - bf2f(bch)), bsl = f2bf(bs - bf2f(bsh));
                    *(unsigned*)&qtH[tokr][2 * mf] = (unsigned)bch | ((unsigned)bsh << 16);
                    *(unsigned*)&qtL[tokr][2 * mf] = (unsigned)bcl | ((unsigned)bsl << 16);
                }
            }
        __syncthreads();

#pragma unroll
        for (int ks = 0; ks < 2; ks++) {
            s8v aH[2], aL[2], bH[2], bL[2];
#pragma unroll
            for (int tau = 0; tau < 2; tau++) {
                int ro = tokb + tau * 16 + m16;
                aH[tau] = *(const s8v*)&qtH[ro][ks * 32 + q * 8];
                aL[tau] = *(const s8v*)&qtL[ro][ks * 32 + q * 8];
            }
#pragma unroll
            for (int nu = 0; nu < 2; nu++) {
                int co = nu * 16 + m16;
                bH[nu] = *(const s8v*)&kvbH[co][ks * 32 + q * 8];
                bL[nu] = *(const s8v*)&kvbL[co][ks * 32 + q * 8];
            }
#pragma unroll
            for (int tau = 0; tau < 2; tau++)
#pragma unroll
                for (int nu = 0; nu < 2; nu++) {
                    acc[tau][nu] = mfma16(aH[tau], bH[nu], acc[tau][nu]);
                    acc[tau][nu] = mfma16(aH[tau], bL[nu], acc[tau][nu]);
                    acc[tau][nu] = mfma16(aL[tau], bH[nu], acc[tau][nu]);
                }
        }
    }

#pragma unroll
    for (int tau = 0; tau < 2; tau++)
#pragma unroll
        for (int nu = 0; nu < 2; nu++)
#pragma unroll
            for (int r = 0; r < 4; r++) {
                int tokr = tokb + tau * 16 + q * 4 + r;
                int e = nu * 16 + m16;
                size_t row = (size_t)(row0 + tokr);
                float val = acc[tau][nu][r];
                unsigned short hv = f2bf(val);
                osplit[row * 512 + h * 32 + e] = hv;
                osplit[row * 512 + 256 + h * 32 + e] = f2bf(val - bf2f(hv));
            }
}

// ================= host =================

extern "C" void kernel_launch(void* const* d_in, const int* in_sizes, int n_in,
                              void* d_out, int out_size, void* d_ws, size_t ws_size,
                              hipStream_t stream)
{
    (void)in_sizes; (void)n_in; (void)out_size; (void)ws_size;
    const float* x    = (const float*)d_in[0];
    const float* cw0  = (const float*)d_in[1];
    const float* cb0  = (const float*)d_in[2];
    const float* cw1  = (const float*)d_in[3];
    const float* cb1  = (const float*)d_in[4];
    const float* cw2  = (const float*)d_in[5];
    const float* cb2  = (const float*)d_in[6];
    const float* Wq   = (const float*)d_in[7];
    const float* bq   = (const float*)d_in[8];
    const float* Wk   = (const float*)d_in[9];
    const float* bk   = (const float*)d_in[10];
    const float* Wv   = (const float*)d_in[11];
    const float* bv   = (const float*)d_in[12];
    const float* Wo   = (const float*)d_in[13];
    const float* bo   = (const float*)d_in[14];
    const float* omega= (const float*)d_in[15];
    const float* gamma= (const float*)d_in[16];
    const float* W1   = (const float*)d_in[17];
    const float* b1   = (const float*)d_in[18];
    const float* W2   = (const float*)d_in[19];
    const float* b2   = (const float*)d_in[20];

    // ws layout — 185 MiB used (ws_size ≈ 256 MiB):
    //   hc      [  0, 16M) f32
    //   qkvc    [ 16, 64M) f32 16384x768
    //   osplit  [ 64, 80M) ushort 16384x512 [hi|lo]
    //   part    [ 80, 96M) f32 64bh x 16sub x 4096
    //   kvfinal [ 96, 97M) f32 64bh x 4096
    //   wqkvt   [ 97, 99M) bf16-split k|v|q|o x 2 layers (r13)
    //   usp     [100,164M) ushort 16384x2048 [hi|lo]
    //   hcs     [164,181M) ushort 16384x512 [hi|lo] centered hc (r4)
    //   w1t     [181,183M) 2 layers (r13)
    //   w2t     [183,185M) 2 layers (r13)
    char* wsb = (char*)d_ws;
    float* hc     = (float*)wsb;
    float* qkvc   = (float*)(wsb + ((size_t)16 << 20));
    unsigned short* osplit = (unsigned short*)(wsb + ((size_t)64 << 20));
    float* part   = (float*)(wsb + ((size_t)80 << 20));
    float* kvfinal= (float*)(wsb + ((size_t)96 << 20));
    unsigned short* wqkvt = (unsigned short*)(wsb + ((size_t)97 << 20));
    unsigned short* usp   = (unsigned short*)(wsb + ((size_t)100 << 20));
    unsigned short* hcs   = (unsigned short*)(wsb + ((size_t)164 << 20));
    unsigned short* w1t   = (unsigned short*)(wsb + ((size_t)181 << 20));
    unsigned short* w2t   = (unsigned short*)(wsb + ((size_t)183 << 20));

    char* dob = (char*)d_out;
    float* h0 = (float*)dob;
    float* h1 = (float*)(dob + ((size_t)8 << 20));

    conv0_kernel<<<(BATCH * L1P + 255) / 256, 256, 0, stream>>>(x, cw0, cb0, h0);
    conv1_kernel<<<(BATCH * L2P + 255) / 256, 256, 0, stream>>>(h0, cw1, cb1, h1);
    conv2_kernel<<<BATCH * SEQ, 256, 0, stream>>>(h1, cw2, cb2, hc);

    // r13: weight preprocessing hoisted -- both layers upfront, 2 dispatches.
    tconv4_kernel<<<dim3(8, 8, 8), 256, 0, stream>>>(Wk, Wv, Wq, Wo, wqkvt);
    tconv_ff_kernel<<<dim3(32, 8, 4), 256, 0, stream>>>(W1, W2, w1t, w2t);

    for (int l = 0; l < 2; l++) {
        const float* bq_l = bq + (size_t)l * DMODEL;
        const float* bk_l = bk + (size_t)l * DMODEL;
        const float* bv_l = bv + (size_t)l * DMODEL;
        const float* bo_l = bo + (size_t)l * DMODEL;
        const float* om_l = omega + (size_t)l * NHEAD * DHEAD * MHALF;
        const float* g_l  = gamma + (size_t)l * NHEAD;
        const float* b1_l = b1 + (size_t)l * DFF;
        const float* b2_l = b2 + (size_t)l * DMODEL;
        unsigned short* wqkvt_l = wqkvt + (size_t)l * 524288;
        unsigned short* wot_l   = wqkvt_l + 3 * 131072;
        unsigned short* w1t_l   = w1t + (size_t)l * 524288;
        unsigned short* w2t_l   = w2t + (size_t)l * 524288;

        // attention — full batch, one dispatch per stage (m fast-varying grids)
        center_split<<<BS_TOK / 64, 256, 0, stream>>>(hc, hcs);
        gemm12864_qkv<<<dim3(BS_TOK / 128, 12), 256, 0, stream>>>(
            hcs, wqkvt_l, bk_l, bv_l, bq_l, qkvc);
        phi_kv_chunk<<<1024, 256, 0, stream>>>(qkvc, om_l, g_l, part);
        kv_reduce<<<1024, 256, 0, stream>>>(part, kvfinal);
        phi_o_chunk<<<1024, 256, 0, stream>>>(qkvc, kvfinal, om_l, g_l, osplit);
        gemm12864<true><<<dim3(BS_TOK / 128, 4), 256, 0, stream>>>(
            osplit, 512, 256, wot_l, 512, 256, bo_l, hc, hc, DMODEL, DMODEL);

        // FF — full batch
        center_split<<<BS_TOK / 64, 256, 0, stream>>>(hc, hcs);
        gemm12864_ff1<<<dim3(BS_TOK / 128, DFF / 64), 256, 0, stream>>>(
            hcs, w1t_l, b1_l, usp);
        float* dest = (l == 1) ? (float*)d_out : hc;
        gemm12864<true><<<dim3(BS_TOK / 128, 4), 256, 0, stream>>>(
            usp, 2048, 1024, w2t_l, 2048, 1024, b2_l, hc, dest, DMODEL, DFF);
    }
}

// Round 15
// 487.641 us; speedup vs baseline: 1.0415x; 1.0415x over previous
//
#include <hip/hip_runtime.h>
#include <hip/hip_bf16.h>
#include <math.h>

#define BATCH 8
#define LRAW 131072
#define L1P 32768
#define L2P 8192
#define SEQ 2048
#define DMODEL 256
#define NHEAD 8
#define DHEAD 32
#define MDIM 128
#define MHALF 64
#define DFF 1024
#define BS_TOK (BATCH*SEQ)
#define INV_SQRT_M 0.08838834764831845f

typedef __attribute__((ext_vector_type(8))) short s8v;   // 8 bf16 (4 VGPRs)
typedef __attribute__((ext_vector_type(4))) float f4v;   // MFMA accumulator

static __device__ __forceinline__ f4v mfma16(s8v a, s8v b, f4v c) {
    return __builtin_amdgcn_mfma_f32_16x16x32_bf16(a, b, c, 0, 0, 0);
}
static __device__ __forceinline__ unsigned short f2bf(float x) {
    __hip_bfloat16 h = __float2bfloat16(x);
    return *reinterpret_cast<unsigned short*>(&h);
}
static __device__ __forceinline__ float bf2f(unsigned short u) {
    __hip_bfloat16 h; *reinterpret_cast<unsigned short*>(&h) = u;
    return __bfloat162float(h);
}
static __device__ __forceinline__ void split8(const float* v, unsigned short* dh, unsigned short* dl) {
#pragma unroll
    for (int j = 0; j < 8; j++) {
        unsigned short hv = f2bf(v[j]);
        dh[j] = hv;
        dl[j] = f2bf(v[j] - bf2f(hv));
    }
}
static __device__ __forceinline__ void split_frag(const float* v, s8v& hi, s8v& lo) {
#pragma unroll
    for (int j = 0; j < 8; j++) {
        unsigned short hv = f2bf(v[j]);
        hi[j] = (short)hv;
        lo[j] = (short)f2bf(v[j] - bf2f(hv));
    }
}
// r5 LDS quad-swizzle (PASSED: conflicts 0 across all GEMMs since r6).
static __device__ __forceinline__ int swz(int row, int kq) {
    return row * 32 + ((kq ^ ((row >> 1) & 3)) << 3);
}
// r9: async global->LDS staging (16B/lane), per-lane pre-swizzled global
// source (m173 pattern). PASSED r10: total 554.8 -> 527.3.
static __device__ __forceinline__ void glds16(const unsigned short* g, unsigned short* l) {
    __builtin_amdgcn_global_load_lds(
        (const __attribute__((address_space(1))) void*)g,
        (__attribute__((address_space(3))) void*)l, 16, 0, 0);
}

// ================= conv stem (PASSED, verbatim) =================

__global__ __launch_bounds__(256) void conv0_kernel(const float* __restrict__ x,
    const float* __restrict__ w, const float* __restrict__ bias, float* __restrict__ out)
{
    int idx = blockIdx.x * 256 + threadIdx.x;
    if (idx >= BATCH * L1P) return;
    int b = idx >> 15;
    int p = idx & (L1P - 1);
    const float* xb = x + (size_t)b * LRAW;
    float acc[8];
#pragma unroll
    for (int c = 0; c < 8; c++) acc[c] = 0.f;
#pragma unroll
    for (int i = 0; i < 4; i++) {
        int base = 4 * p + i - 5;
        float y[8];
#pragma unroll
        for (int c = 0; c < 8; c++) y[c] = bias[c];
#pragma unroll
        for (int kk = 0; kk < 11; kk++) {
            int xi = base + kk;
            float xv = (xi >= 0 && xi < LRAW) ? xb[xi] : 0.f;
#pragma unroll
            for (int c = 0; c < 8; c++) y[c] = fmaf(xv, w[kk * 8 + c], y[c]);
        }
#pragma unroll
        for (int c = 0; c < 8; c++) acc[c] += fmaxf(y[c], 0.f);
    }
    float* op = out + (size_t)idx * 8;
#pragma unroll
    for (int c = 0; c < 8; c++) op[c] = acc[c] * 0.25f;
}

__global__ __launch_bounds__(256) void conv1_kernel(const float* __restrict__ in,
    const float* __restrict__ w, const float* __restrict__ bias, float* __restrict__ out)
{
    int idx = blockIdx.x * 256 + threadIdx.x;
    if (idx >= BATCH * L2P) return;
    int b = idx >> 13;
    int p = idx & (L2P - 1);
    const float* ib = in + (size_t)b * L1P * 8;
    float acc[16];
#pragma unroll
    for (int c = 0; c < 16; c++) acc[c] = 0.f;
#pragma unroll
    for (int i = 0; i < 4; i++) {
        float y[16];
#pragma unroll
        for (int c = 0; c < 16; c++) y[c] = bias[c];
#pragma unroll
        for (int kk = 0; kk < 3; kk++) {
            int pos = 4 * p + i + kk - 1;
            if (pos < 0 || pos >= L1P) continue;
            const float* row = ib + (size_t)pos * 8;
#pragma unroll
            for (int ci = 0; ci < 8; ci++) {
                float xv = row[ci];
#pragma unroll
                for (int c = 0; c < 16; c++) y[c] = fmaf(xv, w[(kk * 8 + ci) * 16 + c], y[c]);
            }
        }
#pragma unroll
        for (int c = 0; c < 16; c++) acc[c] += fmaxf(y[c], 0.f);
    }
    float* op = out + (size_t)idx * 16;
#pragma unroll
    for (int c = 0; c < 16; c++) op[c] = acc[c] * 0.25f;
}

__global__ __launch_bounds__(256) void conv2_kernel(const float* __restrict__ in,
    const float* __restrict__ w, const float* __restrict__ bias, float* __restrict__ out)
{
    int bp = blockIdx.x;
    int b = bp / SEQ, p = bp % SEQ;
    int co = threadIdx.x;
    __shared__ float win[6][16];
    int t = threadIdx.x;
    if (t < 96) {
        int r = t / 16, ci = t % 16;
        int pos = 4 * p - 1 + r;
        win[r][ci] = (pos >= 0 && pos < L2P) ? in[((size_t)b * L2P + pos) * 16 + ci] : 0.f;
    }
    __syncthreads();
    float y[4];
#pragma unroll
    for (int i = 0; i < 4; i++) y[i] = bias[co];
#pragma unroll
    for (int kk = 0; kk < 3; kk++) {
#pragma unroll
        for (int ci = 0; ci < 16; ci++) {
            float wv = w[(kk * 16 + ci) * 256 + co];
#pragma unroll
            for (int i = 0; i < 4; i++) y[i] = fmaf(win[i + kk][ci], wv, y[i]);
        }
    }
    float acc = 0.f;
#pragma unroll
    for (int i = 0; i < 4; i++) acc += fmaxf(y[i], 0.f);
    out[((size_t)b * SEQ + p) * 256 + co] = acc * 0.25f;
}

// ================= batched weight transpose+split (PASSED r10) =================

__global__ __launch_bounds__(256) void tconv4_kernel(
    const float* __restrict__ s0, const float* __restrict__ s1,
    const float* __restrict__ s2, const float* __restrict__ s3,
    unsigned short* __restrict__ dst)
{
    int z = blockIdx.z;
    const float* in = (z == 0) ? s0 : (z == 1) ? s1 : (z == 2) ? s2 : s3;
    unsigned short* outs = dst + (size_t)z * 131072;
    const int R = 256, C = 256;
    __shared__ float tile[32][33];
    int t = threadIdx.x;
    int r0 = blockIdx.y * 32, c0 = blockIdx.x * 32;
    int r = t >> 3, cq = t & 7;
    float4 v = *(const float4*)(in + (size_t)(r0 + r) * C + c0 + cq * 4);
    tile[r][cq * 4 + 0] = v.x; tile[r][cq * 4 + 1] = v.y;
    tile[r][cq * 4 + 2] = v.z; tile[r][cq * 4 + 3] = v.w;
    __syncthreads();
    ushort4 hi, lo;
    unsigned short* hp = (unsigned short*)&hi;
    unsigned short* lp = (unsigned short*)&lo;
#pragma unroll
    for (int j = 0; j < 4; j++) {
        float x = tile[cq * 4 + j][r];
        hp[j] = f2bf(x);
        lp[j] = f2bf(x - bf2f(hp[j]));
    }
    size_t ob = (size_t)(c0 + r) * (2 * R) + r0 + cq * 4;
    *(ushort4*)&outs[ob] = hi;
    *(ushort4*)&outs[ob + R] = lo;
}

__global__ __launch_bounds__(256) void tconv_ff_kernel(
    const float* __restrict__ W1_l, const float* __restrict__ W2_l,
    unsigned short* __restrict__ w1t, unsigned short* __restrict__ w2t)
{
    int z = blockIdx.z;
    int bx = z ? blockIdx.y : blockIdx.x;
    int by = z ? blockIdx.x : blockIdx.y;
    const float* in = z ? W2_l : W1_l;
    unsigned short* outs = z ? w2t : w1t;
    int R = z ? 1024 : 256;
    int C = z ? 256 : 1024;
    __shared__ float tile[32][33];
    int t = threadIdx.x;
    int r0 = by * 32, c0 = bx * 32;
    int r = t >> 3, cq = t & 7;
    float4 v = *(const float4*)(in + (size_t)(r0 + r) * C + c0 + cq * 4);
    tile[r][cq * 4 + 0] = v.x; tile[r][cq * 4 + 1] = v.y;
    tile[r][cq * 4 + 2] = v.z; tile[r][cq * 4 + 3] = v.w;
    __syncthreads();
    ushort4 hi, lo;
    unsigned short* hp = (unsigned short*)&hi;
    unsigned short* lp = (unsigned short*)&lo;
#pragma unroll
    for (int j = 0; j < 4; j++) {
        float x = tile[cq * 4 + j][r];
        hp[j] = f2bf(x);
        lp[j] = f2bf(x - bf2f(hp[j]));
    }
    size_t ob = (size_t)(c0 + r) * (2 * R) + r0 + cq * 4;
    *(ushort4*)&outs[ob] = hi;
    *(ushort4*)&outs[ob + R] = lo;
}

// ================= r4: hoisted LayerCentering + bf16-split =================

__global__ __launch_bounds__(256) void center_split(
    const float* __restrict__ hc, unsigned short* __restrict__ hcs)
{
    __shared__ float psum[64][4];
    __shared__ float muS[64];
    const int t = threadIdx.x;
    const int row = t >> 2, q4 = t & 3;
    const size_t grow = (size_t)blockIdx.x * 64 + row;
    const float* rp = hc + grow * DMODEL + q4 * 64;
    float4 va[16];
    float s = 0.f;
#pragma unroll
    for (int j = 0; j < 16; j++) {
        va[j] = *(const float4*)(rp + j * 4);
        s += va[j].x + va[j].y + va[j].z + va[j].w;
    }
    psum[row][q4] = s;
    __syncthreads();
    if (t < 64) muS[t] = (psum[t][0] + psum[t][1] + psum[t][2] + psum[t][3]) * (1.0f / 256.0f);
    __syncthreads();
    const float mu = muS[row];
    unsigned short* op = hcs + grow * 512 + q4 * 64;
#pragma unroll
    for (int j = 0; j < 8; j++) {
        float v[8] = {va[2*j].x - mu, va[2*j].y - mu, va[2*j].z - mu, va[2*j].w - mu,
                      va[2*j+1].x - mu, va[2*j+1].y - mu, va[2*j+1].z - mu, va[2*j+1].w - mu};
        unsigned short hb[8], lb[8];
        split8(v, hb, lb);
        *(uint4*)(op + j * 8) = *(const uint4*)hb;
        *(uint4*)(op + 256 + j * 8) = *(const uint4*)lb;
    }
}

// ================= split-bf16 MFMA GEMMs =================
// r12 config (best measured: 498.3us): all three large GEMMs on the BK=64
// 128Mx64N double-wide gload_lds structure. r13's weight-prep hoist REGRESSED
// (498.3 -> 507.9) and is reverted; per-layer tconv dispatches restored.

template<bool RESID>
__global__ __launch_bounds__(256) void gemm12864(
    const unsigned short* __restrict__ Abuf, int ARS, int ALO,
    const unsigned short* __restrict__ Bbuf, int BRS, int BLO,
    const float* __restrict__ bias, const float* __restrict__ resid,
    float* __restrict__ C, int N, int K)
{
    __shared__ unsigned short AsH[2][128 * 32];
    __shared__ unsigned short AsL[2][128 * 32];
    __shared__ unsigned short BsH[2][64 * 32];
    __shared__ unsigned short BsL[2][64 * 32];
    const int t = threadIdx.x;
    const int n0 = blockIdx.y * 64, m0 = blockIdx.x * 128;   // m fast-varying
    const int lane = t & 63, w = t >> 6;
    const int wm = w & 1, wn = w >> 1, m16 = lane & 15, q = lane >> 4;
    const f4v fz = {0.f, 0.f, 0.f, 0.f};
    f4v acc[4][2];
#pragma unroll
    for (int i = 0; i < 4; i++)
#pragma unroll
        for (int j = 0; j < 2; j++) acc[i][j] = fz;
    const int rsw = lane >> 2;
    const int kqsw = (((lane & 3) ^ ((lane >> 3) & 3)) << 3);
    const unsigned short* gsrc =
        (w == 0) ? Abuf + (size_t)(m0 + rsw) * ARS + kqsw :
        (w == 1) ? Abuf + (size_t)(m0 + rsw) * ARS + ALO + kqsw :
        (w == 2) ? Bbuf + (size_t)(n0 + rsw) * BRS + kqsw :
                   Bbuf + (size_t)(n0 + rsw) * BRS + BLO + kqsw;
    const int gRS = (w < 2) ? ARS : BRS;
    unsigned short* ldst0 = (w == 0) ? AsH[0] : (w == 1) ? AsL[0] : (w == 2) ? BsH[0] : BsL[0];
    unsigned short* ldst1 = (w == 0) ? AsH[1] : (w == 1) ? AsL[1] : (w == 2) ? BsH[1] : BsL[1];
    for (int k0 = 0; k0 < K; k0 += 64) {
        __syncthreads();
        if (w < 2) {
#pragma unroll
            for (int i = 0; i < 8; i++) {
                glds16(gsrc + (size_t)(i * 16) * gRS + k0, ldst0 + i * 512);
                glds16(gsrc + (size_t)(i * 16) * gRS + k0 + 32, ldst1 + i * 512);
            }
        } else {
#pragma unroll
            for (int i = 0; i < 4; i++) {
                glds16(gsrc + (size_t)(i * 16) * gRS + k0, ldst0 + i * 512);
                glds16(gsrc + (size_t)(i * 16) * gRS + k0 + 32, ldst1 + i * 512);
            }
        }
        __syncthreads();
#pragma unroll
        for (int half = 0; half < 2; half++) {
            s8v ah[4], al[4], bh[2], bl[2];
#pragma unroll
            for (int i = 0; i < 4; i++) {
                int ar = wm * 64 + i * 16 + m16;
                int ro = swz(ar, q);
                ah[i] = *(const s8v*)&AsH[half][ro];
                al[i] = *(const s8v*)&AsL[half][ro];
            }
#pragma unroll
            for (int j = 0; j < 2; j++) {
                int br = wn * 32 + j * 16 + m16;
                int co = swz(br, q);
                bh[j] = *(const s8v*)&BsH[half][co];
                bl[j] = *(const s8v*)&BsL[half][co];
            }
#pragma unroll
            for (int mt = 0; mt < 4; mt++)
#pragma unroll
                for (int nt = 0; nt < 2; nt++) {
                    acc[mt][nt] = mfma16(ah[mt], bh[nt], acc[mt][nt]);
                    acc[mt][nt] = mfma16(ah[mt], bl[nt], acc[mt][nt]);
                    acc[mt][nt] = mfma16(al[mt], bh[nt], acc[mt][nt]);
                }
        }
    }
#pragma unroll
    for (int mt = 0; mt < 4; mt++)
#pragma unroll
        for (int nt = 0; nt < 2; nt++)
#pragma unroll
            for (int r = 0; r < 4; r++) {
                int rg = m0 + wm * 64 + mt * 16 + q * 4 + r;
                int cg = n0 + wn * 32 + nt * 16 + m16;
                float val = acc[mt][nt][r] + bias[cg];
                if (RESID) val += resid[(size_t)rg * N + cg];
                C[(size_t)rg * N + cg] = val;
            }
}

// r11: FF1 on the gemm12864 BK=64 structure; relu + split-bf16 out to usp.
__global__ __launch_bounds__(256) void gemm12864_ff1(
    const unsigned short* __restrict__ Abuf, const unsigned short* __restrict__ Bbuf,
    const float* __restrict__ bias, unsigned short* __restrict__ Us)
{
    __shared__ unsigned short AsH[2][128 * 32];
    __shared__ unsigned short AsL[2][128 * 32];
    __shared__ unsigned short BsH[2][64 * 32];
    __shared__ unsigned short BsL[2][64 * 32];
    const int t = threadIdx.x;
    const int n0 = blockIdx.y * 64, m0 = blockIdx.x * 128;   // m fast-varying
    const int lane = t & 63, w = t >> 6;
    const int wm = w & 1, wn = w >> 1, m16 = lane & 15, q = lane >> 4;
    const f4v fz = {0.f, 0.f, 0.f, 0.f};
    f4v acc[4][2];
#pragma unroll
    for (int i = 0; i < 4; i++)
#pragma unroll
        for (int j = 0; j < 2; j++) acc[i][j] = fz;
    const int rsw = lane >> 2;
    const int kqsw = (((lane & 3) ^ ((lane >> 3) & 3)) << 3);
    const unsigned short* gsrc =
        (w == 0) ? Abuf + (size_t)(m0 + rsw) * 512 + kqsw :
        (w == 1) ? Abuf + (size_t)(m0 + rsw) * 512 + 256 + kqsw :
        (w == 2) ? Bbuf + (size_t)(n0 + rsw) * 512 + kqsw :
                   Bbuf + (size_t)(n0 + rsw) * 512 + 256 + kqsw;
    unsigned short* ldst0 = (w == 0) ? AsH[0] : (w == 1) ? AsL[0] : (w == 2) ? BsH[0] : BsL[0];
    unsigned short* ldst1 = (w == 0) ? AsH[1] : (w == 1) ? AsL[1] : (w == 2) ? BsH[1] : BsL[1];
    for (int k0 = 0; k0 < 256; k0 += 64) {
        __syncthreads();
        if (w < 2) {
#pragma unroll
            for (int i = 0; i < 8; i++) {
                glds16(gsrc + (size_t)(i * 16) * 512 + k0, ldst0 + i * 512);
                glds16(gsrc + (size_t)(i * 16) * 512 + k0 + 32, ldst1 + i * 512);
            }
        } else {
#pragma unroll
            for (int i = 0; i < 4; i++) {
                glds16(gsrc + (size_t)(i * 16) * 512 + k0, ldst0 + i * 512);
                glds16(gsrc + (size_t)(i * 16) * 512 + k0 + 32, ldst1 + i * 512);
            }
        }
        __syncthreads();
#pragma unroll
        for (int half = 0; half < 2; half++) {
            s8v ah[4], al[4], bh[2], bl[2];
#pragma unroll
            for (int i = 0; i < 4; i++) {
                int ar = wm * 64 + i * 16 + m16;
                int ro = swz(ar, q);
                ah[i] = *(const s8v*)&AsH[half][ro];
                al[i] = *(const s8v*)&AsL[half][ro];
            }
#pragma unroll
            for (int j = 0; j < 2; j++) {
                int br = wn * 32 + j * 16 + m16;
                int co = swz(br, q);
                bh[j] = *(const s8v*)&BsH[half][co];
                bl[j] = *(const s8v*)&BsL[half][co];
            }
#pragma unroll
            for (int mt = 0; mt < 4; mt++)
#pragma unroll
                for (int nt = 0; nt < 2; nt++) {
                    acc[mt][nt] = mfma16(ah[mt], bh[nt], acc[mt][nt]);
                    acc[mt][nt] = mfma16(ah[mt], bl[nt], acc[mt][nt]);
                    acc[mt][nt] = mfma16(al[mt], bh[nt], acc[mt][nt]);
                }
        }
    }
#pragma unroll
    for (int mt = 0; mt < 4; mt++)
#pragma unroll
        for (int nt = 0; nt < 2; nt++)
#pragma unroll
            for (int r = 0; r < 4; r++) {
                int rg = m0 + wm * 64 + mt * 16 + q * 4 + r;
                int cg = n0 + wn * 32 + nt * 16 + m16;
                float val = fmaxf(acc[mt][nt][r] + bias[cg], 0.f);
                unsigned short hv = f2bf(val);
                Us[(size_t)rg * 2048 + cg] = hv;
                Us[(size_t)rg * 2048 + 1024 + cg] = f2bf(val - bf2f(hv));
            }
}

// r12: QKV on the gemm12864 BK=64 structure; bias-select epilogue, C f32.
__global__ __launch_bounds__(256) void gemm12864_qkv(
    const unsigned short* __restrict__ Abuf, const unsigned short* __restrict__ Bbuf,
    const float* __restrict__ bk, const float* __restrict__ bv, const float* __restrict__ bq,
    float* __restrict__ C)
{
    __shared__ unsigned short AsH[2][128 * 32];
    __shared__ unsigned short AsL[2][128 * 32];
    __shared__ unsigned short BsH[2][64 * 32];
    __shared__ unsigned short BsL[2][64 * 32];
    const int t = threadIdx.x;
    const int n0 = blockIdx.y * 64, m0 = blockIdx.x * 128;   // m fast-varying
    const int lane = t & 63, w = t >> 6;
    const int wm = w & 1, wn = w >> 1, m16 = lane & 15, q = lane >> 4;
    const f4v fz = {0.f, 0.f, 0.f, 0.f};
    f4v acc[4][2];
#pragma unroll
    for (int i = 0; i < 4; i++)
#pragma unroll
        for (int j = 0; j < 2; j++) acc[i][j] = fz;
    const int rsw = lane >> 2;
    const int kqsw = (((lane & 3) ^ ((lane >> 3) & 3)) << 3);
    const unsigned short* gsrc =
        (w == 0) ? Abuf + (size_t)(m0 + rsw) * 512 + kqsw :
        (w == 1) ? Abuf + (size_t)(m0 + rsw) * 512 + 256 + kqsw :
        (w == 2) ? Bbuf + (size_t)(n0 + rsw) * 512 + kqsw :
                   Bbuf + (size_t)(n0 + rsw) * 512 + 256 + kqsw;
    unsigned short* ldst0 = (w == 0) ? AsH[0] : (w == 1) ? AsL[0] : (w == 2) ? BsH[0] : BsL[0];
    unsigned short* ldst1 = (w == 0) ? AsH[1] : (w == 1) ? AsL[1] : (w == 2) ? BsH[1] : BsL[1];
    for (int k0 = 0; k0 < 256; k0 += 64) {
        __syncthreads();
        if (w < 2) {
#pragma unroll
            for (int i = 0; i < 8; i++) {
                glds16(gsrc + (size_t)(i * 16) * 512 + k0, ldst0 + i * 512);
                glds16(gsrc + (size_t)(i * 16) * 512 + k0 + 32, ldst1 + i * 512);
            }
        } else {
#pragma unroll
            for (int i = 0; i < 4; i++) {
                glds16(gsrc + (size_t)(i * 16) * 512 + k0, ldst0 + i * 512);
                glds16(gsrc + (size_t)(i * 16) * 512 + k0 + 32, ldst1 + i * 512);
            }
        }
        __syncthreads();
#pragma unroll
        for (int half = 0; half < 2; half++) {
            s8v ah[4], al[4], bh[2], bl[2];
#pragma unroll
            for (int i = 0; i < 4; i++) {
                int ar = wm * 64 + i * 16 + m16;
                int ro = swz(ar, q);
                ah[i] = *(const s8v*)&AsH[half][ro];
                al[i] = *(const s8v*)&AsL[half][ro];
            }
#pragma unroll
            for (int j = 0; j < 2; j++) {
                int br = wn * 32 + j * 16 + m16;
                int co = swz(br, q);
                bh[j] = *(const s8v*)&BsH[half][co];
                bl[j] = *(const s8v*)&BsL[half][co];
            }
#pragma unroll
            for (int mt = 0; mt < 4; mt++)
#pragma unroll
                for (int nt = 0; nt < 2; nt++) {
                    acc[mt][nt] = mfma16(ah[mt], bh[nt], acc[mt][nt]);
                    acc[mt][nt] = mfma16(ah[mt], bl[nt], acc[mt][nt]);
                    acc[mt][nt] = mfma16(al[mt], bh[nt], acc[mt][nt]);
                }
        }
    }
    const float* bp = (n0 < 256) ? bk : (n0 < 512) ? (bv - 256) : (bq - 512);
#pragma unroll
    for (int mt = 0; mt < 4; mt++)
#pragma unroll
        for (int nt = 0; nt < 2; nt++)
#pragma unroll
            for (int r = 0; r < 4; r++) {
                int rg = m0 + wm * 64 + mt * 16 + q * 4 + r;
                int cg = n0 + wn * 32 + nt * 16 + m16;
                C[(size_t)rg * 768 + cg] = acc[mt][nt][r] + bp[cg];
            }
}

// ================= phi kernels =================

// r6: full-MFMA phi_kv (PASSED r7: left the top-5, total -39us).
__global__ __launch_bounds__(256) void phi_kv_chunk(
    const float* __restrict__ qkv, const float* __restrict__ om_l,
    const float* __restrict__ g_l, float* __restrict__ part)
{
    __shared__ unsigned short ktTH[128 * 40];  // [feature m][tok], pitch 40
    __shared__ unsigned short ktTL[128 * 40];
    __shared__ unsigned short vTH[32 * 40];    // [e][tok], pitch 40
    __shared__ unsigned short vTL[32 * 40];

    const int bx = blockIdx.x;
    const int sub = bx & 15;
    const int bh = bx >> 4;               // 0..63
    const int b = bh >> 3, h = bh & 7;
    const int t = threadIdx.x;
    const float g = g_l[h];
    const int row0 = b * 2048 + sub * 128;

    const int w = t >> 6, lane = t & 63, m16 = lane & 15, q = lane >> 4;
    const int mh = w * 16 + m16;          // wave's proj feature column (0..63)
    const int ve = t & 31, vtq = t >> 5;  // vT staging: e, tok-base

    // om B-frags, loaded once (tok-independent): row mh, k = d = q*8+jj
    s8v obh, obl;
    {
        const float* op = om_l + (size_t)h * 2048 + (q * 8) * 64 + mh;
        float vv[8];
#pragma unroll
        for (int jj = 0; jj < 8; jj++) vv[jj] = op[jj * 64];
        split_frag(vv, obh, obl);
    }
    const float slope = 2.0f - (float)mh * 0.03125f;

    const f4v fz = {0.f, 0.f, 0.f, 0.f};
    f4v acc[2][2] = {{fz, fz}, {fz, fz}};

    for (int step = 0; step < 4; step++) {
        if (step) __syncthreads();        // prior GEMM reads must finish

        // stage vT (transpose + split): coalesced reads, conflict-free writes
#pragma unroll
        for (int j = 0; j < 4; j++) {
            int tok = vtq + 8 * j;
            float v = qkv[(size_t)(row0 + step * 32 + tok) * 768 + 256 + h * 32 + ve];
            unsigned short hv = f2bf(v);
            vTH[ve * 40 + tok] = hv;
            vTL[ve * 40 + tok] = f2bf(v - bf2f(hv));
        }

        // proj MFMA: proj[tok][mh] ; A = k rows from global (L2-hot)
        f4v pr[2] = {fz, fz};
#pragma unroll
        for (int tau = 0; tau < 2; tau++) {
            const float* kp = qkv + (size_t)(row0 + step * 32 + tau * 16 + m16) * 768 + h * 32 + q * 8;
            float4 v0 = *(const float4*)kp;
            float4 v1 = *(const float4*)(kp + 4);
            float vv[8] = {v0.x, v0.y, v0.z, v0.w, v1.x, v1.y, v1.z, v1.w};
            s8v kah, kal;
            split_frag(vv, kah, kal);
            pr[tau] = mfma16(kah, obh, pr[tau]);
            pr[tau] = mfma16(kah, obl, pr[tau]);
            pr[tau] = mfma16(kal, obh, pr[tau]);
        }

        // trig + ktT writes: lane owns (tok = tau*16+q*4+r, feature mh / 64+mh)
#pragma unroll
        for (int tau = 0; tau < 2; tau++)
#pragma unroll
            for (int r = 0; r < 4; r++) {
                int tokl = tau * 16 + q * 4 + r;
                float t_s = (float)(sub * 128 + step * 32 + tokl) * (1.0f / 2047.0f);
                float proj = pr[tau][r];
                float ec = INV_SQRT_M * __expf(-g * t_s * slope);
                float es = INV_SQRT_M * __expf(-g * (1.0f - t_s) * slope);
                float bc = __cosf(proj) * ec;
                float bs = __sinf(proj) * es;
                unsigned short bch = f2bf(bc), bsh = f2bf(bs);
                unsigned short bcl = f2bf(bc - bf2f(bch)), bsl = f2bf(bs - bf2f(bsh));
                ktTH[mh * 40 + tokl] = bch;
                ktTL[mh * 40 + tokl] = bcl;
                ktTH[(64 + mh) * 40 + tokl] = bsh;
                ktTL[(64 + mh) * 40 + tokl] = bsl;
            }
        __syncthreads();

        // GEMM: kv[m][e] += ktT x vT^T over this step's 32 tokens
        s8v aH[2], aL[2], bH[2], bL[2];
#pragma unroll
        for (int tau = 0; tau < 2; tau++) {
            int ro = (w * 32 + tau * 16 + m16) * 40 + q * 8;
            aH[tau] = *(const s8v*)&ktTH[ro];
            aL[tau] = *(const s8v*)&ktTL[ro];
        }
#pragma unroll
        for (int nu = 0; nu < 2; nu++) {
            int co = (nu * 16 + m16) * 40 + q * 8;
            bH[nu] = *(const s8v*)&vTH[co];
            bL[nu] = *(const s8v*)&vTL[co];
        }
#pragma unroll
        for (int tau = 0; tau < 2; tau++)
#pragma unroll
            for (int nu = 0; nu < 2; nu++) {
                acc[tau][nu] = mfma16(aH[tau], bH[nu], acc[tau][nu]);
                acc[tau][nu] = mfma16(aH[tau], bL[nu], acc[tau][nu]);
                acc[tau][nu] = mfma16(aL[tau], bH[nu], acc[tau][nu]);
            }
    }

    // write partial kv: lane (tau,nu,r) -> part[m = w*32+tau*16+q*4+r][e = nu*16+m16]
    float* pp = part + (size_t)(bh * 16 + sub) * 4096;
#pragma unroll
    for (int tau = 0; tau < 2; tau++)
#pragma unroll
        for (int nu = 0; nu < 2; nu++)
#pragma unroll
            for (int r = 0; r < 4; r++) {
                int m = w * 32 + tau * 16 + q * 4 + r;
                int e = nu * 16 + m16;
                pp[m * 32 + e] = acc[tau][nu][r];
            }
}

// 1024 blocks (64 bh x 16 seg); independent-batch loads, fixed-order sum
__global__ __launch_bounds__(256) void kv_reduce(const float* __restrict__ part,
    float* __restrict__ kvf)
{
    int bh = blockIdx.x >> 4;
    int seg = blockIdx.x & 15;
    int i = seg * 256 + threadIdx.x;
    const float* base = part + (size_t)(bh * 16) * 4096 + i;
    float v[16];
#pragma unroll
    for (int sub = 0; sub < 16; sub++)
        v[sub] = base[(size_t)sub * 4096];
    float s = 0.f;
#pragma unroll
    for (int sub = 0; sub < 16; sub++) s += v[sub];
    kvf[(size_t)bh * 4096 + i] = s;
}

// r3: full-MFMA phi_o (PASSED r4: left the top-5).
__global__ __launch_bounds__(256, 3) void phi_o_chunk(
    const float* __restrict__ qkv, const float* __restrict__ kvf,
    const float* __restrict__ om_l, const float* __restrict__ g_l,
    unsigned short* __restrict__ osplit)
{
    __shared__ unsigned short qtH[128][72];   // [tok][lm] lm=2*mf(+1): cos/sin interleaved
    __shared__ unsigned short qtL[128][72];
    __shared__ unsigned short kvbH[32][72];   // [e][lm], same interleave
    __shared__ unsigned short kvbL[32][72];

    const int bx = blockIdx.x;
    const int sub = bx & 15;
    const int bh = bx >> 4;               // 0..63
    const int b = bh >> 3, h = bh & 7;
    const int t = threadIdx.x;
    const float g = g_l[h];
    const int row0 = b * 2048 + sub * 128;

    const int w = t >> 6, lane = t & 63, m16 = lane & 15, q = lane >> 4;
    const int tokb = w * 32;              // wave's 32-token slice

    // q A-frags, loaded once (reused by both passes): tile tau: rows tokb+tau*16+m16
    s8v qah[2], qal[2];
#pragma unroll
    for (int tau = 0; tau < 2; tau++) {
        const float* qp = qkv + (size_t)(row0 + tokb + tau * 16 + m16) * 768 + 512 + h * 32 + q * 8;
        float4 v0 = *(const float4*)qp;
        float4 v1 = *(const float4*)(qp + 4);
        float vv[8] = {v0.x, v0.y, v0.z, v0.w, v1.x, v1.y, v1.z, v1.w};
        split_frag(vv, qah[tau], qal[tau]);
    }

    const f4v fz = {0.f, 0.f, 0.f, 0.f};
    f4v acc[2][2] = {{fz, fz}, {fz, fz}};

    for (int p = 0; p < 2; p++) {
        if (p) __syncthreads();           // prev phase-C reads must finish

        // stage kv^T (split, interleaved): 4 (cos,sin) pairs per thread
#pragma unroll
        for (int vi = 0; vi < 4; vi++) {
            int pidx = t + vi * 256;      // 0..1023
            int e = pidx & 31, j = pidx >> 5;   // j = pass-local feature 0..31
            float c = kvf[(size_t)bh * 4096 + (p * 32 + j) * 32 + e];
            float s = kvf[(size_t)bh * 4096 + (64 + p * 32 + j) * 32 + e];
            unsigned short ch = f2bf(c), sh = f2bf(s);
            unsigned short cl = f2bf(c - bf2f(ch)), sl = f2bf(s - bf2f(sh));
            *(unsigned*)&kvbH[e][2 * j] = (unsigned)ch | ((unsigned)sh << 16);
            *(unsigned*)&kvbL[e][2 * j] = (unsigned)cl | ((unsigned)sl << 16);
        }

        // om^T B-frags for this pass: row mf = mu*16+m16, k = d = q*8+jj
        s8v obh[2], obl[2];
#pragma unroll
        for (int mu = 0; mu < 2; mu++) {
            int mh_g = p * 32 + mu * 16 + m16;
            const float* op = om_l + (size_t)h * 2048 + (q * 8) * 64 + mh_g;
            float vv[8];
#pragma unroll
            for (int jj = 0; jj < 8; jj++) vv[jj] = op[jj * 64];
            split_frag(vv, obh[mu], obl[mu]);
        }

        // proj MFMA: proj[tok][mf]
        f4v pr[2][2] = {{fz, fz}, {fz, fz}};
#pragma unroll
        for (int tau = 0; tau < 2; tau++)
#pragma unroll
            for (int mu = 0; mu < 2; mu++) {
                pr[tau][mu] = mfma16(qah[tau], obh[mu], pr[tau][mu]);
                pr[tau][mu] = mfma16(qah[tau], obl[mu], pr[tau][mu]);
                pr[tau][mu] = mfma16(qal[tau], obh[mu], pr[tau][mu]);
            }

        // trig + packed qt writes: lane owns (tok = tokb+tau*16+q*4+r, mf = mu*16+m16)
#pragma unroll
        for (int tau = 0; tau < 2; tau++)
#pragma unroll
            for (int mu = 0; mu < 2; mu++) {
                int mf = mu * 16 + m16;
                int mh_g = p * 32 + mf;
                float slope = 2.0f - (float)mh_g * 0.03125f;
#pragma unroll
                for (int r = 0; r < 4; r++) {
                    int tokr = tokb + tau * 16 + q * 4 + r;
                    float t_s = (float)(sub * 128 + tokr) * (1.0f / 2047.0f);
                    float proj = pr[tau][mu][r];
                    float ec = INV_SQRT_M * __expf(g * t_s * slope);
                    float es = INV_SQRT_M * __expf(g * (1.0f - t_s) * slope);
                    float bc = __cosf(proj) * ec;
                    float bs = __sinf(proj) * es;
                    unsigned short bch = f2bf(bc), bsh = f2bf(bs);
                    unsigned short bcl = f2bf(bc - bf2f(bch)), bsl = f2bf(bs - bf2f(bsh));
                    *(unsigned*)&qtH[tokr][2 * mf] = (unsigned)bch | ((unsigned)bsh << 16);
                    *(unsigned*)&qtL[tokr][2 * mf] = (unsigned)bcl | ((unsigned)bsl << 16);
                }
            }
        __syncthreads();

        // phase C MFMA: O[tok][e] += qt x kv^T over 64 interleaved k
#pragma unroll
        for (int ks = 0; ks < 2; ks++) {
            s8v aH[2], aL[2], bH[2], bL[2];
#pragma unroll
            for (int tau = 0; tau < 2; tau++) {
                int ro = tokb + tau * 16 + m16;
                aH[tau] = *(const s8v*)&qtH[ro][ks * 32 + q * 8];
                aL[tau] = *(const s8v*)&qtL[ro][ks * 32 + q * 8];
            }
#pragma unroll
            for (int nu = 0; nu < 2; nu++) {
                int co = nu * 16 + m16;
                bH[nu] = *(const s8v*)&kvbH[co][ks * 32 + q * 8];
                bL[nu] = *(const s8v*)&kvbL[co][ks * 32 + q * 8];
            }
#pragma unroll
            for (int tau = 0; tau < 2; tau++)
#pragma unroll
                for (int nu = 0; nu < 2; nu++) {
                    acc[tau][nu] = mfma16(aH[tau], bH[nu], acc[tau][nu]);
                    acc[tau][nu] = mfma16(aH[tau], bL[nu], acc[tau][nu]);
                    acc[tau][nu] = mfma16(aL[tau], bH[nu], acc[tau][nu]);
                }
        }
    }

    // epilogue: split-bf16 output (lane: tok = tokb+tau*16+q*4+r, e = nu*16+m16)
#pragma unroll
    for (int tau = 0; tau < 2; tau++)
#pragma unroll
        for (int nu = 0; nu < 2; nu++)
#pragma unroll
            for (int r = 0; r < 4; r++) {
                int tokr = tokb + tau * 16 + q * 4 + r;
                int e = nu * 16 + m16;
                size_t row = (size_t)(row0 + tokr);
                float val = acc[tau][nu][r];
                unsigned short hv = f2bf(val);
                osplit[row * 512 + h * 32 + e] = hv;
                osplit[row * 512 + 256 + h * 32 + e] = f2bf(val - bf2f(hv));
            }
}

// ================= host =================

extern "C" void kernel_launch(void* const* d_in, const int* in_sizes, int n_in,
                              void* d_out, int out_size, void* d_ws, size_t ws_size,
                              hipStream_t stream)
{
    (void)in_sizes; (void)n_in; (void)out_size; (void)ws_size;
    const float* x    = (const float*)d_in[0];
    const float* cw0  = (const float*)d_in[1];
    const float* cb0  = (const float*)d_in[2];
    const float* cw1  = (const float*)d_in[3];
    const float* cb1  = (const float*)d_in[4];
    const float* cw2  = (const float*)d_in[5];
    const float* cb2  = (const float*)d_in[6];
    const float* Wq   = (const float*)d_in[7];
    const float* bq   = (const float*)d_in[8];
    const float* Wk   = (const float*)d_in[9];
    const float* bk   = (const float*)d_in[10];
    const float* Wv   = (const float*)d_in[11];
    const float* bv   = (const float*)d_in[12];
    const float* Wo   = (const float*)d_in[13];
    const float* bo   = (const float*)d_in[14];
    const float* omega= (const float*)d_in[15];
    const float* gamma= (const float*)d_in[16];
    const float* W1   = (const float*)d_in[17];
    const float* b1   = (const float*)d_in[18];
    const float* W2   = (const float*)d_in[19];
    const float* b2   = (const float*)d_in[20];

    // ws layout — 181 MiB used (ws_size ≈ 256 MiB):
    //   hc      [  0, 16M) f32
    //   qkvc    [ 16, 64M) f32 16384x768
    //   osplit  [ 64, 80M) ushort 16384x512 [hi|lo]
    //   part    [ 80, 96M) f32 64bh x 16sub x 4096
    //   kvfinal [ 96, 97M) f32 64bh x 4096
    //   wqkvt   [ 97, 98M) bf16-split k|v|q|o (4 x 131072 ushorts)
    //   w1t/w2t [ 98,100M)
    //   usp     [100,164M) ushort 16384x2048 [hi|lo]
    //   hcs     [164,181M) ushort 16384x512 [hi|lo] centered hc (r4)
    char* wsb = (char*)d_ws;
    float* hc     = (float*)wsb;
    float* qkvc   = (float*)(wsb + ((size_t)16 << 20));
    unsigned short* osplit = (unsigned short*)(wsb + ((size_t)64 << 20));
    float* part   = (float*)(wsb + ((size_t)80 << 20));
    float* kvfinal= (float*)(wsb + ((size_t)96 << 20));
    unsigned short* wqkvt = (unsigned short*)(wsb + ((size_t)97 << 20));
    unsigned short* wot   = wqkvt + 3 * 131072;
    unsigned short* w1t   = (unsigned short*)(wsb + ((size_t)98 << 20));
    unsigned short* w2t   = w1t + 524288;
    unsigned short* usp   = (unsigned short*)(wsb + ((size_t)100 << 20));
    unsigned short* hcs   = (unsigned short*)(wsb + ((size_t)164 << 20));

    // d_out: stem scratch only (h0 [0,8M), h1 [8,12M)); final output written
    // directly by layer-1 FF2.
    char* dob = (char*)d_out;
    float* h0 = (float*)dob;
    float* h1 = (float*)(dob + ((size_t)8 << 20));

    conv0_kernel<<<(BATCH * L1P + 255) / 256, 256, 0, stream>>>(x, cw0, cb0, h0);
    conv1_kernel<<<(BATCH * L2P + 255) / 256, 256, 0, stream>>>(h0, cw1, cb1, h1);
    conv2_kernel<<<BATCH * SEQ, 256, 0, stream>>>(h1, cw2, cb2, hc);

    for (int l = 0; l < 2; l++) {
        const float* Wq_l = Wq + (size_t)l * DMODEL * DMODEL;
        const float* bq_l = bq + (size_t)l * DMODEL;
        const float* Wk_l = Wk + (size_t)l * DMODEL * DMODEL;
        const float* bk_l = bk + (size_t)l * DMODEL;
        const float* Wv_l = Wv + (size_t)l * DMODEL * DMODEL;
        const float* bv_l = bv + (size_t)l * DMODEL;
        const float* Wo_l = Wo + (size_t)l * DMODEL * DMODEL;
        const float* bo_l = bo + (size_t)l * DMODEL;
        const float* om_l = omega + (size_t)l * NHEAD * DHEAD * MHALF;
        const float* g_l  = gamma + (size_t)l * NHEAD;
        const float* W1_l = W1 + (size_t)l * DMODEL * DFF;
        const float* b1_l = b1 + (size_t)l * DFF;
        const float* W2_l = W2 + (size_t)l * DFF * DMODEL;
        const float* b2_l = b2 + (size_t)l * DMODEL;

        // attention — full batch, one dispatch per stage (m fast-varying grids)
        tconv4_kernel<<<dim3(8, 8, 4), 256, 0, stream>>>(Wk_l, Wv_l, Wq_l, Wo_l, wqkvt);
        center_split<<<BS_TOK / 64, 256, 0, stream>>>(hc, hcs);
        gemm12864_qkv<<<dim3(BS_TOK / 128, 12), 256, 0, stream>>>(
            hcs, wqkvt, bk_l, bv_l, bq_l, qkvc);
        phi_kv_chunk<<<1024, 256, 0, stream>>>(qkvc, om_l, g_l, part);
        kv_reduce<<<1024, 256, 0, stream>>>(part, kvfinal);
        phi_o_chunk<<<1024, 256, 0, stream>>>(qkvc, kvfinal, om_l, g_l, osplit);
        gemm12864<true><<<dim3(BS_TOK / 128, 4), 256, 0, stream>>>(
            osplit, 512, 256, wot, 512, 256, bo_l, hc, hc, DMODEL, DMODEL);

        // FF — full batch
        tconv_ff_kernel<<<dim3(32, 8, 2), 256, 0, stream>>>(W1_l, W2_l, w1t, w2t);
        center_split<<<BS_TOK / 64, 256, 0, stream>>>(hc, hcs);
        gemm12864_ff1<<<dim3(BS_TOK / 128, DFF / 64), 256, 0, stream>>>(
            hcs, w1t, b1_l, usp);
        float* dest = (l == 1) ? (float*)d_out : hc;
        gemm12864<true><<<dim3(BS_TOK / 128, 4), 256, 0, stream>>>(
            usp, 2048, 1024, w2t, 2048, 1024, b2_l, hc, dest, DMODEL, DFF);
    }
}